// Round 1
// baseline (998.345 us; speedup 1.0000x reference)
//
#include <hip/hip_runtime.h>
#include <stdint.h>
#include <stddef.h>

// MaskedLinear: y = x @ W.T + b, rows zeroed where amask==0.
// N=1e6, IN=OUT=128, fp32 in/out. bf16 MFMA compute (2% absmax budget).
//
// R3: occupancy fix. Previous version pinned all of W as bf16 B-fragments in
// 128 VGPRs -> ~200 VGPR total -> 2 waves/SIMD. Kernel dispatch (~149us,
// inferred: dur_us minus the two 322us harness poison fills) ran at only
// ~5.2 TB/s effective vs 6.3 achievable -> latency/burstiness, not BW limit.
// Now W lives in LDS (32 KB) as per-(fragment,lane) contiguous 16B entries:
// the per-MFMA operand read is a canonical conflict-free ds_read_b128.
// VGPR drops to ~90 -> __launch_bounds__(256,4) -> 4 waves/SIMD, 4 blocks/CU
// (LDS cap 160/32=5), grid 1024 blocks so they're resident. Output stores are
// nontemporal (pure write-once stream).
//
// Layout facts carried from verified version:
//  - A/B frag: lane holds m/n = lane&15, k = (lane>>4)*8 + j  (16x16x32 bf16)
//  - C/D (m89): col = lane&15, row = (lane>>4)*4 + reg
//  - amask is 4-byte words; test word != 0 (int {0,1} or float {0.0,1.0}).

typedef __attribute__((ext_vector_type(8))) short short8;   // 8 bf16 = 4 VGPRs
typedef __attribute__((ext_vector_type(4))) float f32x4;    // MFMA acc / vec4 load

__device__ __forceinline__ unsigned short f2bf(float f) {
    union { float f; unsigned int u; } v; v.f = f;
    unsigned int u = v.u;
    // round-to-nearest-even
    unsigned int r = (u + 0x7FFFu + ((u >> 16) & 1u)) >> 16;
    return (unsigned short)r;
}

__device__ __forceinline__ short8 pack8(f32x4 lo, f32x4 hi) {
    short8 r;
    r[0] = (short)f2bf(lo[0]); r[1] = (short)f2bf(lo[1]);
    r[2] = (short)f2bf(lo[2]); r[3] = (short)f2bf(lo[3]);
    r[4] = (short)f2bf(hi[0]); r[5] = (short)f2bf(hi[1]);
    r[6] = (short)f2bf(hi[2]); r[7] = (short)f2bf(hi[3]);
    return r;
}

__global__ __launch_bounds__(256, 4)
void masked_linear_kernel(const float* __restrict__ x,
                          const int* __restrict__ amask,
                          const float* __restrict__ W,
                          const float* __restrict__ bias,
                          float* __restrict__ out,
                          int n_tiles, int n_waves)
{
    // 32 fragments (t=0..7 col-tiles x s=0..3 k-tiles) x 64 lanes x 16 B
    __shared__ short8 wlds[2048];   // 32 KiB

    const int tid  = threadIdx.x;
    const int lane = tid & 63;
    const int wid  = blockIdx.x * (blockDim.x >> 6) + (tid >> 6);
    const int ln   = lane & 15;   // m (A row) / n (B col) / C col index
    const int kg   = lane >> 4;   // k-group (0..3)

    // ---- stage W -> LDS as bf16 B-fragments ----
    // entry e = f*64 + l, f = t*4+s. Content for reading-lane l:
    //   B[k][n] = W[n][k], n = t*16 + (l&15), k = s*32 + (l>>4)*8 + j
    for (int e = tid; e < 2048; e += 256) {
        const int f = e >> 6, l = e & 63;
        const int t = f >> 2, s = f & 3;
        const int n  = t * 16 + (l & 15);
        const int k0 = s * 32 + (l >> 4) * 8;
        const f32x4* p = reinterpret_cast<const f32x4*>(W + n * 128 + k0);
        wlds[e] = pack8(p[0], p[1]);
    }
    float bv[8];
#pragma unroll
    for (int t = 0; t < 8; ++t) bv[t] = bias[t * 16 + ln];
    __syncthreads();

    for (int tile = wid; tile < n_tiles; tile += n_waves) {
        const int r0   = tile << 4;
        const int arow = r0 + ln;                 // row this lane loads (A frag)
        const bool m   = amask[arow] != 0;        // 4-byte word test
        // store rows for this lane: r0 + kg*4 + {0..3}; 4 int32 words, aligned
        const int4 smask =
            *reinterpret_cast<const int4*>(amask + r0 + (kg << 2));

        // ---- A fragments: predicated direct-from-global loads ----
        const float* xr = x + (size_t)arow * 128 + kg * 8;
        short8 a[4];
#pragma unroll
        for (int s = 0; s < 4; ++s) {
            f32x4 lo = {0.f, 0.f, 0.f, 0.f};
            f32x4 hi = {0.f, 0.f, 0.f, 0.f};
            if (m) {
                const f32x4* p = reinterpret_cast<const f32x4*>(xr + s * 32);
                lo = p[0]; hi = p[1];
            }
            a[s] = pack8(lo, hi);
        }

        // ---- acc init with bias (same col for all 4 regs) ----
        f32x4 acc[8];
#pragma unroll
        for (int t = 0; t < 8; ++t) {
            f32x4 v = {bv[t], bv[t], bv[t], bv[t]};
            acc[t] = v;
        }
        // ---- MFMA: B fragment straight from LDS (ds_read_b128, no conflicts)
#pragma unroll
        for (int s = 0; s < 4; ++s)
#pragma unroll
            for (int t = 0; t < 8; ++t)
                acc[t] = __builtin_amdgcn_mfma_f32_16x16x32_bf16(
                             a[s], wlds[(t * 4 + s) * 64 + lane], acc[t], 0, 0, 0);

        // ---- store: row=(lane>>4)*4+r, col=t*16+ln; zero masked-out rows ----
        // nontemporal: 512 MB write-once stream, keep it out of L2.
        float* orow = out + (size_t)(r0 + (kg << 2)) * 128 + ln;
        const int km[4] = {smask.x, smask.y, smask.z, smask.w};
#pragma unroll
        for (int r = 0; r < 4; ++r) {
            const bool keep = km[r] != 0;
            float* op = orow + (size_t)r * 128;
#pragma unroll
            for (int t = 0; t < 8; ++t)
                __builtin_nontemporal_store(keep ? acc[t][r] : 0.0f, op + t * 16);
        }
    }
}

extern "C" void kernel_launch(void* const* d_in, const int* in_sizes, int n_in,
                              void* d_out, int out_size, void* d_ws, size_t ws_size,
                              hipStream_t stream) {
    const float* x     = (const float*)d_in[0];
    const int*   amask = (const int*)d_in[1];
    const float* W     = (const float*)d_in[2];
    const float* b     = (const float*)d_in[3];
    float*       out   = (float*)d_out;

    const int n_rows  = in_sizes[1];      // 1,000,000 (multiple of 16)
    const int n_tiles = n_rows >> 4;      // 62,500
    // 4 blocks/CU resident (VGPR<=128, LDS 32KB): 256 CU * 4 = 1024 blocks.
    const int blocks  = 1024;
    const int n_waves = blocks * 4;

    hipLaunchKernelGGL(masked_linear_kernel, dim3(blocks), dim3(256), 0, stream,
                       x, amask, W, b, out, n_tiles, n_waves);
}